// Round 11
// baseline (682.381 us; speedup 1.0000x reference)
//
#include <hip/hip_runtime.h>
#include <math.h>

#define PI_F 3.14159265358979323846f

// LDS padding: +1 complex slot every 16.
#define FI(i) ((i) + ((i) >> 4))
#define TSTRIDE 546  // tile row stride (1092 words; %32==4 -> <=2-way banks)

__device__ inline float2 cmulf(float2 a, float2 b) {
    return make_float2(a.x * b.x - a.y * b.y, a.x * b.y + a.y * b.x);
}
__device__ inline float2 cadd(float2 a, float2 b) { return make_float2(a.x + b.x, a.y + b.y); }
__device__ inline float2 csub(float2 a, float2 b) { return make_float2(a.x - b.x, a.y - b.y); }

__device__ inline void cmac(float2& a, float2 w, float2 v) {
    a.x = fmaf(w.x, v.x, a.x);
    a.x = fmaf(-w.y, v.y, a.x);
    a.y = fmaf(w.x, v.y, a.y);
    a.y = fmaf(w.y, v.x, a.y);
}

// Bijective chunked XCD remap (grid % 8 == 0).
__device__ inline int xcd_remap(int bid, int q) {
    return (bid & 7) * q + (bid >> 3);
}

// ---------- wave radix-8 primitives ----------
__device__ inline void wave_fence() {
    asm volatile("s_waitcnt lgkmcnt(0)" ::: "memory");
    __builtin_amdgcn_sched_barrier(0);
}

template <bool INV>
__device__ inline float2 rot90(float2 z) {
    return INV ? make_float2(-z.y, z.x) : make_float2(z.y, -z.x);
}

template <bool INV>
__device__ inline void dft8(float2 v[8]) {
    const float R2 = 0.70710678118654752f;
    float2 t0 = cadd(v[0], v[4]), t1 = csub(v[0], v[4]);
    float2 t2 = cadd(v[2], v[6]), t3 = csub(v[2], v[6]);
    float2 s0 = cadd(v[1], v[5]), s1 = csub(v[1], v[5]);
    float2 s2 = cadd(v[3], v[7]), s3 = csub(v[3], v[7]);
    float2 rt3 = rot90<INV>(t3), rs3 = rot90<INV>(s3);
    float2 E0 = cadd(t0, t2), E1 = cadd(t1, rt3), E2 = csub(t0, t2), E3 = csub(t1, rt3);
    float2 O0 = cadd(s0, s2), O1 = cadd(s1, rs3), O2 = csub(s0, s2), O3 = csub(s1, rs3);
    float2 rO1 = rot90<INV>(O1), rO2 = rot90<INV>(O2), rO3 = rot90<INV>(O3);
    float2 a1 = make_float2(R2 * (O1.x + rO1.x), R2 * (O1.y + rO1.y));
    float2 a2 = rO2;
    float2 a3 = make_float2(R2 * (rO3.x - O3.x), R2 * (rO3.y - O3.y));
    v[0] = cadd(E0, O0); v[4] = csub(E0, O0);
    v[1] = cadd(E1, a1); v[5] = csub(E1, a1);
    v[2] = cadd(E2, a2); v[6] = csub(E2, a2);
    v[3] = cadd(E3, a3); v[7] = csub(E3, a3);
}

__device__ inline void twiddle8(float2 v[8], float2 w1) {
    float2 w2 = cmulf(w1, w1);
    float2 w3 = cmulf(w2, w1);
    float2 w4 = cmulf(w2, w2);
    float2 w5 = cmulf(w4, w1);
    float2 w6 = cmulf(w3, w3);
    float2 w7 = cmulf(w4, w3);
    v[1] = cmulf(v[1], w1); v[2] = cmulf(v[2], w2); v[3] = cmulf(v[3], w3);
    v[4] = cmulf(v[4], w4); v[5] = cmulf(v[5], w5); v[6] = cmulf(v[6], w6);
    v[7] = cmulf(v[7], w7);
}

// 512-pt radix-8^3 Stockham, one wave, IN-PLACE in R (FI-indexed row).
// v[] = x[lane+64j] on entry, X[lane+64m] natural order on exit.
template <bool INV>
__device__ inline void fft512_wave_ip(float2 v[8], float2* R, int lane) {
    const float sg = INV ? (6.2831853071795865f / 512.0f)
                         : (-6.2831853071795865f / 512.0f);
    float2 w1;
    __sincosf(sg * (float)lane, &w1.y, &w1.x);
    dft8<INV>(v);
    twiddle8(v, w1);
#pragma unroll
    for (int m = 0; m < 8; ++m) R[FI(8 * lane + m)] = v[m];
    wave_fence();
#pragma unroll
    for (int j = 0; j < 8; ++j) v[j] = R[FI(lane + 64 * j)];
    float2 w1b;
    w1b.x = __shfl(w1.x, lane & 56);
    w1b.y = __shfl(w1.y, lane & 56);
    dft8<INV>(v);
    twiddle8(v, w1b);
    {
        int ob = (lane & 7) + ((lane >> 3) << 6);
#pragma unroll
        for (int m = 0; m < 8; ++m) R[FI(ob + 8 * m)] = v[m];
    }
    wave_fence();
#pragma unroll
    for (int j = 0; j < 8; ++j) v[j] = R[FI(lane + 64 * j)];
    dft8<INV>(v);
}

// K1: real FFT of rows via PAIR-PACKING (round-9 form, unchanged).
__global__ __launch_bounds__(256) void k_row_rfft(const float* __restrict__ x,
                                                  float2* __restrict__ G) {
    __shared__ float2 lds[4][544];
    int lane = threadIdx.x & 63;
    int w = threadIdx.x >> 6;
    int pair = blockIdx.x * 4 + w;
    const float* x0 = x + (size_t)(2 * pair) * 512;
    const float* x1 = x0 + 512;
    float2 v[8];
#pragma unroll
    for (int j = 0; j < 8; ++j)
        v[j] = make_float2(x0[lane + 64 * j], x1[lane + 64 * j]);
    fft512_wave_ip<false>(v, lds[w], lane);
    float2 P[5];
#pragma unroll
    for (int m = 0; m < 5; ++m) {
        int src = (64 - lane) & 63;
        float2 p;
        p.x = __shfl(v[7 - m].x, src);
        p.y = __shfl(v[7 - m].y, src);
        if (lane == 0) p = v[(8 - m) & 7];
        P[m] = p;
    }
    float2* g0 = G + (size_t)(2 * pair) * 257;
    float2* g1 = g0 + 257;
#pragma unroll
    for (int m = 0; m < 4; ++m) {
        int k = lane + 64 * m;
        float2 Z = v[m], Pc = P[m];
        float2 S = make_float2(0.5f * (Z.x + Pc.x), 0.5f * (Z.y - Pc.y));
        float2 D = make_float2(Z.x - Pc.x, Z.y + Pc.y);
        float2 T = make_float2(0.5f * D.y, -0.5f * D.x);
        g0[k] = S;
        g1[k] = T;
    }
    if (lane == 0) {
        float2 Z = v[4], Pc = P[4];
        g0[256] = make_float2(0.5f * (Z.x + Pc.x), 0.5f * (Z.y - Pc.y));
        float2 D = make_float2(Z.x - Pc.x, Z.y + Pc.y);
        g1[256] = make_float2(0.5f * D.y, -0.5f * D.x);
    }
}

// K2: FFT along h for 16 v-columns per block (round-8 form, unchanged).
__global__ __launch_bounds__(1024) void k_col_fft(const float2* __restrict__ G,
                                                  float2* __restrict__ XT) {
    __shared__ float2 tile[16][TSTRIDE];
    int tid = threadIdx.x;
    int l = xcd_remap(blockIdx.x, 272);  // grid = 2176 = 128 nc * 17 vt
    int nc = l / 17;
    int v0 = (l % 17) * 16;
#pragma unroll
    for (int j = 0; j < 8; ++j) {
        int e = tid + 1024 * j;
        int dv = e & 15, h = e >> 4;
        int v = v0 + dv;
        float2 val = make_float2(0.0f, 0.0f);
        if (v < 257) val = G[((size_t)nc * 512 + h) * 257 + v];
        tile[dv][FI(h)] = val;
    }
    __syncthreads();
    int lane = tid & 63, w = tid >> 6;
    float2* R = tile[w];
    float2 vv[8];
#pragma unroll
    for (int j = 0; j < 8; ++j) vv[j] = R[FI(lane + 64 * j)];
    fft512_wave_ip<false>(vv, R, lane);
    int v = v0 + w;
    if (v < 257) {
        float2* dst = XT + ((size_t)nc * 257 + v) * 512;
#pragma unroll
        for (int m = 0; m < 8; ++m) dst[lane + 64 * m] = vv[m];
    }
}

// K3+K4 FUSED: per block = one (n, v): complex 3x3 conv over the FULL
// 512-u row for all 16 output channels, then 16 in-LDS u-IFFTs, writing
// ZT directly. Eliminates the 270-MB YT round trip.
// 512 threads (8 waves). Thread t owns u=t, acc[16] in regs. Weights
// wave-uniform s_loads, IDENTICAL across waves (sK$ streaming shared).
// X staged in 4-channel groups (49.5 KB -> 3 blocks/CU, 24 waves).
// Epilogue: 2 rounds x 8 o: acc -> LDS transpose -> wave-per-o IFFT
// (in-place radix-8) -> coalesced ZT row store with 1/512 scale.
__global__ __launch_bounds__(512, 6) void k_conv_ifft(const float2* __restrict__ XT,
                                                      float2* __restrict__ ZT,
                                                      const float* __restrict__ wr,
                                                      const float* __restrict__ wi,
                                                      const float* __restrict__ br,
                                                      const float* __restrict__ bi) {
    __shared__ float2 smem[4 * 3 * 516];  // 49536 B; epilogue uses 8*544 <= this
    int tid = threadIdx.x;
    int l = xcd_remap(blockIdx.x, 257);   // grid = 2056 = 8 n * 257 v
    int v = l % 257;
    int n = l / 257;

    float2 acc[16];
#pragma unroll
    for (int o = 0; o < 16; ++o)
        acc[o] = make_float2(br[o], bi[o]);

    for (int cg = 0; cg < 4; ++cg) {
        __syncthreads();  // protect smem reuse (first iter harmless)
        for (int s = tid; s < 6168; s += 512) {
            int c = s / 1542;
            int rem = s - c * 1542;
            int dv = rem / 514;
            int uu = rem - dv * 514;
            int vg = v - 1 + dv;
            int ug = uu - 1;
            float2 val = make_float2(0.0f, 0.0f);
            if (vg >= 0 && vg < 257 && ug >= 0 && ug < 512)
                val = XT[(((size_t)n * 16 + cg * 4 + c) * 257 + vg) * 512 + ug];
            smem[(c * 3 + dv) * 516 + uu] = val;
        }
        __syncthreads();

        for (int c = 0; c < 4; ++c) {
            int cgc = cg * 4 + c;
            float2 xv[3][3];
#pragma unroll
            for (int dv = 0; dv < 3; ++dv) {
                const float2* row = &smem[(c * 3 + dv) * 516];
                xv[dv][0] = row[tid];
                xv[dv][1] = row[tid + 1];
                xv[dv][2] = row[tid + 2];
            }
#pragma unroll
            for (int o = 0; o < 16; ++o) {
                const float* wrp = wr + ((size_t)(cgc * 16 + o)) * 9;
                const float* wip = wi + ((size_t)(cgc * 16 + o)) * 9;
                float wre[9], wim[9];
#pragma unroll
                for (int t = 0; t < 9; ++t) { wre[t] = wrp[t]; wim[t] = wip[t]; }
#pragma unroll
                for (int kw = 0; kw < 3; ++kw) {
#pragma unroll
                    for (int kh = 0; kh < 3; ++kh) {
                        int t = kh * 3 + kw;
                        float2 w = make_float2(wre[t], wim[t]);
                        cmac(acc[o], w, xv[2 - kw][2 - kh]);
                    }
                }
            }
        }
    }

    // Epilogue: u-IFFT of the 16 Y rows, 8 at a time.
    int lane = tid & 63;
    int wvid = tid >> 6;  // wave id 0..7
    const float sc = 1.0f / 512.0f;
    for (int r = 0; r < 2; ++r) {
        __syncthreads();  // smem free / previous round done
#pragma unroll
        for (int k = 0; k < 8; ++k)
            smem[k * 544 + FI(tid)] = acc[r * 8 + k];
        __syncthreads();
        float2* R = smem + wvid * 544;  // wave-private row (o = r*8 + wvid)
        float2 vv[8];
#pragma unroll
        for (int j = 0; j < 8; ++j) vv[j] = R[FI(lane + 64 * j)];
        fft512_wave_ip<true>(vv, R, lane);
        float2* dst = ZT + (((size_t)n * 16 + r * 8 + wvid) * 257 + v) * 512;
#pragma unroll
        for (int m = 0; m < 8; ++m)
            dst[lane + 64 * m] = make_float2(vv[m].x * sc, vv[m].y * sc);
    }
}

// K5: irfft along v via PAIR-UNPACKING (round-9 form, unchanged).
__global__ __launch_bounds__(512) void k_row_irfft(const float2* __restrict__ ZT,
                                                   float* __restrict__ out) {
    __shared__ float2 tile[16][TSTRIDE];
    int tid = threadIdx.x;
    int no = blockIdx.x >> 5;        // grid = 128 * 32
    int h0 = (blockIdx.x & 31) * 16;
#pragma unroll
    for (int j = 0; j < 9; ++j) {
        int e = tid + 512 * j;       // over 257*16 = 4112
        if (e < 4112) {
            int dh = e & 15, vv = e >> 4;
            tile[dh][FI(vv)] = ZT[((size_t)no * 257 + vv) * 512 + h0 + dh];
        }
    }
    __syncthreads();
    int lane = tid & 63, w = tid >> 6;  // pair rows 2w, 2w+1
    float2* Ra = tile[2 * w];
    float2* Rb = tile[2 * w + 1];
    float2 v[8];
#pragma unroll
    for (int m = 0; m < 8; ++m) {
        int i = lane + 64 * m;
        float2 a, b, W;
        if (i <= 256) {
            a = Ra[FI(i)];
            b = Rb[FI(i)];
            if (i == 0 || i == 256) { a.y = 0.0f; b.y = 0.0f; }
            W = make_float2(a.x - b.y, a.y + b.x);
        } else {
            int ii = 512 - i;
            a = Ra[FI(ii)];
            b = Rb[FI(ii)];
            W = make_float2(a.x + b.y, -a.y + b.x);
        }
        v[m] = W;
    }
    fft512_wave_ip<true>(v, Ra, lane);
    const float sc = 1.0f / 512.0f;
    float* d0 = out + ((size_t)no * 512 + h0 + 2 * w) * 512;
    float* d1 = d0 + 512;
#pragma unroll
    for (int m = 0; m < 8; ++m) {
        d0[lane + 64 * m] = v[m].x * sc;
        d1[lane + 64 * m] = v[m].y * sc;
    }
}

extern "C" void kernel_launch(void* const* d_in, const int* in_sizes, int n_in,
                              void* d_out, int out_size, void* d_ws, size_t ws_size,
                              hipStream_t stream) {
    const float* x  = (const float*)d_in[0];
    const float* wr = (const float*)d_in[1];
    const float* wi = (const float*)d_in[2];
    const float* br = (const float*)d_in[3];
    const float* bi = (const float*)d_in[4];
    float* out = (float*)d_out;

    const size_t bufElems = (size_t)128 * 257 * 512;  // complex elements
    float2* A = (float2*)d_ws;
    float2* B = A + bufElems;

    k_row_rfft<<<8192, 256, 0, stream>>>(x, A);                        // x -> G (A)
    k_col_fft<<<128 * 17, 1024, 0, stream>>>(A, B);                    // G -> XT (B)
    k_conv_ifft<<<8 * 257, 512, 0, stream>>>(B, A, wr, wi, br, bi);    // XT -> ZT (A)
    k_row_irfft<<<128 * 32, 512, 0, stream>>>(A, out);                 // ZT -> out
}